// Round 6
// baseline (70.160 us; speedup 1.0000x reference)
//
#include <hip/hip_runtime.h>
#include <math.h>

// Problem constants (match reference)
constexpr int B_ = 32, Q_ = 500, N_ = 200, K_ = 16, C_ = 92;
constexpr int TWO_K = 32;
constexpr int THREADS = 512;     // one thread per q (500 used)
constexpr int NR = 13;           // n-slice per block
constexpr int NSPLIT = 16;       // 16*13 = 208 >= 200 (tail clamped+guarded)
constexpr int TST = 36;          // sT row stride in floats (144 B, 16B-aligned)
constexpr float EPS_ = 1e-6f;
constexpr float POLY_SCALE = 5.0f / 32.0f;   // POLY_COST / (2K)

__device__ __forceinline__ float rcpf_(float x) { return __builtin_amdgcn_rcpf(x); }

__global__ __launch_bounds__(THREADS, 4)     // cap VGPR at 128 -> 4 waves/SIMD
void matcher_cost_kernel(const float* __restrict__ logits,   // (B,Q,C)
                         const float* __restrict__ ppoly,    // (B,Q,K,2)
                         const int*   __restrict__ labels,   // (B,N)
                         const float* __restrict__ tpoly,    // (B,N,K,2)
                         float* __restrict__ out)            // (B,Q,N)
{
    __shared__ float sT[NR * TST];   // 13 target rows (1872 B)
    __shared__ float sTB[NR * 8];    // tgt bbox(4)+area, 32B rows (416 B)
    __shared__ int   sLbl[NR];

    const int tid = threadIdx.x;
    const int ns  = blockIdx.x;      // n-slice
    const int b   = blockIdx.y;      // batch
    const int n0  = ns * NR;
    const int qc  = min(tid, Q_ - 1);

    // ---------- stage: 13 target rows (104 threads, one float4 each) ----------
    if (tid < NR * 8) {
        int r = tid >> 3, c = tid & 7;
        int nsrc = min(n0 + r, N_ - 1);
        float4 v = reinterpret_cast<const float4*>(
            tpoly + (size_t)(b * N_ + nsrc) * TWO_K)[c];
        *reinterpret_cast<float4*>(&sT[r * TST + c * 4]) = v;   // 16B-aligned
    }
    if (tid < NR) sLbl[tid] = labels[b * N_ + min(n0 + tid, N_ - 1)];

    // ---------- softmax scalars for this thread's q (two-pass, L3-cached) ----------
    const float* lg  = logits + (size_t)(b * Q_ + qc) * C_;
    const float4* lg4 = reinterpret_cast<const float4*>(lg);
    float mx = -INFINITY;
    #pragma unroll
    for (int j = 0; j < 23; ++j) {
        float4 v = lg4[j];
        mx = fmaxf(mx, fmaxf(fmaxf(v.x, v.y), fmaxf(v.z, v.w)));
    }
    float ssum = 0.0f;
    #pragma unroll
    for (int j = 0; j < 23; ++j) {
        float4 v = lg4[j];
        ssum += __expf(v.x - mx) + __expf(v.y - mx) + __expf(v.z - mx) + __expf(v.w - mx);
    }
    const float rs = 1.0f / ssum;

    // ---------- pred polyline + bbox (registers) ----------
    float px[K_], py[K_];
    float pxm = INFINITY, pxM = -INFINITY, pym = INFINITY, pyM = -INFINITY;
    {
        const float4* pr = reinterpret_cast<const float4*>(
            ppoly + (size_t)(b * Q_ + qc) * TWO_K);
        #pragma unroll
        for (int m = 0; m < 8; ++m) {
            float4 v = pr[m];
            px[2 * m] = v.x;  py[2 * m] = v.y;
            px[2 * m + 1] = v.z;  py[2 * m + 1] = v.w;
            pxm = fminf(pxm, fminf(v.x, v.z)); pxM = fmaxf(pxM, fmaxf(v.x, v.z));
            pym = fminf(pym, fminf(v.y, v.w)); pyM = fmaxf(pyM, fmaxf(v.y, v.w));
        }
    }
    const float parea = (pxM - pxm) * (pyM - pym);

    __syncthreads();   // sT, sLbl ready

    // ---------- tgt bboxes: 8 threads per n, shuffle-8 reduce ----------
    if (tid < NR * 8) {
        int g = tid >> 3, sub = tid & 7;
        float4 p = *reinterpret_cast<const float4*>(&sT[g * TST + sub * 4]);
        float xm = fminf(p.x, p.z), xM = fmaxf(p.x, p.z);
        float ym = fminf(p.y, p.w), yM = fmaxf(p.y, p.w);
        #pragma unroll
        for (int off = 4; off; off >>= 1) {
            xm = fminf(xm, __shfl_xor(xm, off, 8));
            xM = fmaxf(xM, __shfl_xor(xM, off, 8));
            ym = fminf(ym, __shfl_xor(ym, off, 8));
            yM = fmaxf(yM, __shfl_xor(yM, off, 8));
        }
        if (sub == 0) {
            sTB[g * 8 + 0] = xm; sTB[g * 8 + 1] = ym;
            sTB[g * 8 + 2] = xM; sTB[g * 8 + 3] = yM;
            sTB[g * 8 + 4] = (xM - xm) * (yM - ym);
        }
    }

    // ---------- per-thread class costs for the 13 n (register-resident) ----------
    float cls[NR];
    #pragma unroll
    for (int j = 0; j < NR; ++j) {
        int lbl = sLbl[j];                    // broadcast LDS read
        cls[j] = __expf(lg[lbl] - mx) * rs;   // L2-cached gather
    }

    __syncthreads();   // sTB ready

    float* orow = out + (size_t)(b * Q_ + tid) * N_ + n0;   // guarded below
    const bool qok = (tid < Q_);

    // ---------- main loop: fully unrolled, pure-VALU + broadcast LDS ----------
    #pragma unroll
    for (int j = 0; j < NR; ++j) {
        const float4* tr4 = reinterpret_cast<const float4*>(&sT[j * TST]);
        float f0 = 0, f1 = 0, r0 = 0, r1 = 0;   // 4 indep chains
        #pragma unroll
        for (int m = 0; m < 8; ++m) {
            float4 t = tr4[m];                  // broadcast ds_read_b128, imm offset
            const int k0 = 2 * m, k1 = 2 * m + 1;
            f0 += fabsf(px[k0] - t.x) + fabsf(py[k0] - t.y);
            f1 += fabsf(px[k1] - t.z) + fabsf(py[k1] - t.w);
            r0 += fabsf(px[15 - k0] - t.x) + fabsf(py[15 - k0] - t.y);
            r1 += fabsf(px[15 - k1] - t.z) + fabsf(py[15 - k1] - t.w);
        }
        float cpoly = fminf(f0 + f1, r0 + r1);

        float tx0 = sTB[j * 8 + 0], ty0 = sTB[j * 8 + 1];
        float tx1 = sTB[j * 8 + 2], ty1 = sTB[j * 8 + 3];
        float ta  = sTB[j * 8 + 4];
        float ix0 = fmaxf(pxm, tx0), iy0 = fmaxf(pym, ty0);
        float ix1 = fminf(pxM, tx1), iy1 = fminf(pyM, ty1);
        float inter = fmaxf(ix1 - ix0, 0.0f) * fmaxf(iy1 - iy0, 0.0f);
        float uni = parea + ta - inter;
        float iou = inter * rcpf_(fmaxf(uni, EPS_));
        float cx0 = fminf(pxm, tx0), cy0 = fminf(pym, ty0);
        float cx1 = fmaxf(pxM, tx1), cy1 = fmaxf(pyM, ty1);
        float ca = (cx1 - cx0) * (cy1 - cy0);
        float giou = iou - (ca - uni) * rcpf_(fmaxf(ca, EPS_));

        float val = fmaf(cpoly, POLY_SCALE, -cls[j]) - giou;
        if (qok && (n0 + j) < N_) orow[j] = val;
    }
}

extern "C" void kernel_launch(void* const* d_in, const int* in_sizes, int n_in,
                              void* d_out, int out_size, void* d_ws, size_t ws_size,
                              hipStream_t stream) {
    const float* logits = (const float*)d_in[0];   // (B,Q,C)
    const float* ppoly  = (const float*)d_in[1];   // (B,Q,K,2)
    const int*   labels = (const int*)d_in[2];     // (B,N)
    const float* tpoly  = (const float*)d_in[3];   // (B,N,K,2)
    float* out = (float*)d_out;                    // (B,Q,N)

    dim3 grid(NSPLIT, B_);                         // (16, 32) = 512 blocks
    matcher_cost_kernel<<<grid, THREADS, 0, stream>>>(logits, ppoly, labels, tpoly, out);
}

// Round 8
// 27.497 us; speedup vs baseline: 2.5516x; 2.5516x over previous
//
#include <hip/hip_runtime.h>
#include <math.h>

typedef __fp16 h2 __attribute__((ext_vector_type(2)));   // native builtin elt type

// Problem constants (match reference)
constexpr int B_ = 32, Q_ = 500, N_ = 200, K_ = 16, C_ = 92;
constexpr int TWO_K = 32;
constexpr int THREADS = 512;
constexpr int QT = 64;          // q per block (= lane)
constexpr int NT = 50;          // n per block (4 splits * 50 = 200, no tail)
constexpr int PSH = 66;         // sPh row stride (halfs), odd-dword -> conflict-free
constexpr int OS = 51;          // sOut row stride (floats), odd -> 2-way free
constexpr float EPS_ = 1e-6f;
constexpr float POLY_SCALE = 5.0f / 32.0f;

__device__ __forceinline__ h2 habs2_(h2 x) {
    unsigned u; __builtin_memcpy(&u, &x, 4); u &= 0x7fff7fffu;
    h2 r; __builtin_memcpy(&r, &u, 4); return r;
}
__device__ __forceinline__ h2 pk2_(float a, float b) {
    return __builtin_amdgcn_cvt_pkrtz(a, b);
}
__device__ __forceinline__ float dot2acc_(h2 a, float acc) {
#if __has_builtin(__builtin_amdgcn_fdot2)
    const h2 one2 = {(__fp16)1.0f, (__fp16)1.0f};
    return __builtin_amdgcn_fdot2(a, one2, acc, false);
#else
    return acc + (float)a[0] + (float)a[1];
#endif
}
__device__ __forceinline__ float rcpf_(float x) { return __builtin_amdgcn_rcpf(x); }

__global__ __launch_bounds__(THREADS, 8)     // target VGPR <= 64 -> 8 waves/SIMD
void matcher_cost_kernel(const float* __restrict__ logits,   // (B,Q,C)
                         const float* __restrict__ ppoly,    // (B,Q,K,2)
                         const int*   __restrict__ labels,   // (B,N)
                         const float* __restrict__ tpoly,    // (B,N,K,2)
                         float* __restrict__ out)            // (B,Q,N)
{
    __shared__ uint4  sTh4[NT * 4];    // f16 targets, 64B/row      (3200 B)
    __shared__ float  sTB[NT * 8];     // bbox(4)+area, 32B rows    (1600 B)
    __shared__ int    sLbl[NT];        //                            (200 B)
    __shared__ __fp16 sPh[C_ * PSH];   // probs, transposed [c][q] (12144 B)
    __shared__ float  sOut[QT * OS];   // output tile [q][n]       (13056 B)
    // total 30200 B -> 5 blocks/CU by LDS; grid gives 4/CU -> 32 waves/CU

    const int tid  = threadIdx.x;
    const int w    = tid >> 6;
    const int lane = tid & 63;
    const int n0   = blockIdx.x * NT;
    const int q0   = blockIdx.y * QT;
    const int b    = blockIdx.z;

    // ---------- stage targets (f32->f16) + tgt bbox (400 threads) ----------
    if (tid < NT * 8) {
        int r = tid >> 3, c = tid & 7;
        float4 v = reinterpret_cast<const float4*>(
            tpoly + (size_t)(b * N_ + n0 + r) * TWO_K)[c];
        uint2 u;
        h2 h0 = pk2_(v.x, v.y), h1 = pk2_(v.z, v.w);
        __builtin_memcpy(&u.x, &h0, 4); __builtin_memcpy(&u.y, &h1, 4);
        reinterpret_cast<uint2*>(sTh4)[r * 8 + c] = u;

        float xm = fminf(v.x, v.z), xM = fmaxf(v.x, v.z);
        float ym = fminf(v.y, v.w), yM = fmaxf(v.y, v.w);
        #pragma unroll
        for (int off = 4; off; off >>= 1) {
            xm = fminf(xm, __shfl_xor(xm, off, 8));
            xM = fmaxf(xM, __shfl_xor(xM, off, 8));
            ym = fminf(ym, __shfl_xor(ym, off, 8));
            yM = fmaxf(yM, __shfl_xor(yM, off, 8));
        }
        if (c == 0) {
            sTB[r * 8 + 0] = xm; sTB[r * 8 + 1] = ym;
            sTB[r * 8 + 2] = xM; sTB[r * 8 + 3] = yM;
            sTB[r * 8 + 4] = (xM - xm) * (yM - ym);
        }
    }
    if (tid < NT) sLbl[tid] = labels[b * N_ + n0 + tid];

    // ---------- softmax for 64 q (8 threads/q), write transposed f16 probs ----------
    {
        int g = tid >> 3, sub = tid & 7;
        int qg = min(q0 + g, Q_ - 1);
        const float* lg = logits + (size_t)(b * Q_ + qg) * C_;
        float v[12]; float mx = -INFINITY;
        #pragma unroll
        for (int j = 0; j < 12; ++j) {
            int c = sub + 8 * j;
            v[j] = (c < C_) ? lg[c] : -INFINITY;
            mx = fmaxf(mx, v[j]);
        }
        #pragma unroll
        for (int off = 4; off; off >>= 1) mx = fmaxf(mx, __shfl_xor(mx, off, 8));
        float s = 0.0f;
        #pragma unroll
        for (int j = 0; j < 12; ++j) {
            int c = sub + 8 * j;
            if (c < C_) { v[j] = __expf(v[j] - mx); s += v[j]; }
        }
        #pragma unroll
        for (int off = 4; off; off >>= 1) s += __shfl_xor(s, off, 8);
        float rs = 1.0f / s;
        #pragma unroll
        for (int j = 0; j < 12; ++j) {
            int c = sub + 8 * j;
            if (c < C_) sPh[c * PSH + g] = (__fp16)(v[j] * rs);
        }
    }

    // ---------- per-thread pred polyline (q = q0+lane), f16 packed + f32 bbox ----------
    const int qc = min(q0 + lane, Q_ - 1);
    h2 ph[K_];
    float pxm = INFINITY, pxM = -INFINITY, pym = INFINITY, pyM = -INFINITY;
    {
        const float4* pr4 = reinterpret_cast<const float4*>(
            ppoly + (size_t)(b * Q_ + qc) * TWO_K);
        #pragma unroll
        for (int m = 0; m < 8; ++m) {
            float4 v = pr4[m];
            ph[2 * m]     = pk2_(v.x, v.y);
            ph[2 * m + 1] = pk2_(v.z, v.w);
            pxm = fminf(pxm, fminf(v.x, v.z)); pxM = fmaxf(pxM, fmaxf(v.x, v.z));
            pym = fminf(pym, fminf(v.y, v.w)); pyM = fmaxf(pyM, fmaxf(v.y, v.w));
        }
    }
    const float parea = (pxM - pxm) * (pyM - pym);

    __syncthreads();   // sTh4, sTB, sLbl, sPh ready

    // ---------- main loop: wave-uniform n, broadcast LDS, packed-f16 L1 ----------
    for (int nl = w; nl < NT; nl += 8) {
        uint4 ta_ = sTh4[nl * 4 + 0], tb_ = sTh4[nl * 4 + 1];
        uint4 tc_ = sTh4[nl * 4 + 2], td_ = sTh4[nl * 4 + 3];
        unsigned tw[16] = {ta_.x, ta_.y, ta_.z, ta_.w,  tb_.x, tb_.y, tb_.z, tb_.w,
                           tc_.x, tc_.y, tc_.z, tc_.w,  td_.x, td_.y, td_.z, td_.w};
        float f0 = 0, f1 = 0, r0 = 0, r1 = 0;   // 4 indep f32 accum chains
        #pragma unroll
        for (int k = 0; k < K_; ++k) {
            h2 t; __builtin_memcpy(&t, &tw[k], 4);
            h2 d1 = ph[k] - t;                   // v_pk_sub (or pk_add with neg)
            h2 d2 = ph[15 - k] - t;
            if (k & 1) { f1 = dot2acc_(habs2_(d1), f1); r1 = dot2acc_(habs2_(d2), r1); }
            else       { f0 = dot2acc_(habs2_(d1), f0); r0 = dot2acc_(habs2_(d2), r0); }
        }
        float cpoly = fminf(f0 + f1, r0 + r1);

        int lbl = sLbl[nl];                                   // broadcast
        float pr = (float)sPh[lbl * PSH + lane];              // conflict-free gather

        float4 tb4 = *reinterpret_cast<const float4*>(&sTB[nl * 8]);  // broadcast b128
        float ta  = sTB[nl * 8 + 4];
        float ix0 = fmaxf(pxm, tb4.x), iy0 = fmaxf(pym, tb4.y);
        float ix1 = fminf(pxM, tb4.z), iy1 = fminf(pyM, tb4.w);
        float inter = fmaxf(ix1 - ix0, 0.0f) * fmaxf(iy1 - iy0, 0.0f);
        float uni = parea + ta - inter;
        float iou = inter * rcpf_(fmaxf(uni, EPS_));
        float cx0 = fminf(pxm, tb4.x), cy0 = fminf(pym, tb4.y);
        float cx1 = fmaxf(pxM, tb4.z), cy1 = fmaxf(pyM, tb4.w);
        float ca = (cx1 - cx0) * (cy1 - cy0);
        float giou = iou - (ca - uni) * rcpf_(fmaxf(ca, EPS_));

        sOut[lane * OS + nl] = fmaf(cpoly, POLY_SCALE, -pr) - giou;
    }
    __syncthreads();

    // ---------- coalesced store of the [64 q][50 n] tile ----------
    {
        int r = tid >> 3, sub = tid & 7;
        int q = q0 + r;
        if (q < Q_) {
            float* orow = out + ((size_t)(b * Q_ + q)) * N_ + n0;
            #pragma unroll
            for (int j = 0; j < 7; ++j) {
                int c = sub + 8 * j;
                if (c < NT) orow[c] = sOut[r * OS + c];
            }
        }
    }
}

extern "C" void kernel_launch(void* const* d_in, const int* in_sizes, int n_in,
                              void* d_out, int out_size, void* d_ws, size_t ws_size,
                              hipStream_t stream) {
    const float* logits = (const float*)d_in[0];   // (B,Q,C)
    const float* ppoly  = (const float*)d_in[1];   // (B,Q,K,2)
    const int*   labels = (const int*)d_in[2];     // (B,N)
    const float* tpoly  = (const float*)d_in[3];   // (B,N,K,2)
    float* out = (float*)d_out;                    // (B,Q,N)

    dim3 grid(N_ / NT, (Q_ + QT - 1) / QT, B_);    // (4, 8, 32) = 1024 blocks
    matcher_cost_kernel<<<grid, THREADS, 0, stream>>>(logits, ppoly, labels, tpoly, out);
}